// Round 1
// baseline (2064.610 us; speedup 1.0000x reference)
//
#include <hip/hip_runtime.h>

typedef float f32x4 __attribute__((ext_vector_type(4)));
typedef __bf16 bf16x8 __attribute__((ext_vector_type(8)));
typedef unsigned short u16;
typedef u16 u16x4 __attribute__((ext_vector_type(4)));

// ---------- helpers ----------

__device__ __forceinline__ u16 f2bf(float x) {
  union { float f; unsigned int u; } v; v.f = x;
  unsigned int u = v.u;
  return (u16)((u + 0x7FFFu + ((u >> 16) & 1u)) >> 16);  // RNE
}

__device__ __forceinline__ void gld_lds16(const void* g, void* l) {
  // async global->LDS, 16B per lane; LDS dest must be wave-uniform base + lane*16
  __builtin_amdgcn_global_load_lds((const __attribute__((address_space(1))) void*)g,
                                   (__attribute__((address_space(3))) void*)l,
                                   16, 0, 0);
}

// ---------- small kernels ----------

// route4[e*T + t] = sum_k topk_weights[t,k] * (topk_ids[t,k] % 4 == e), e in [0,4)
__global__ __launch_bounds__(256) void route_kernel(const int* __restrict__ ids,
                                                    const float* __restrict__ wts,
                                                    float* __restrict__ route4,
                                                    int T, int K) {
  int t = blockIdx.x * 256 + threadIdx.x;
  if (t >= T) return;
  float r[4] = {0.f, 0.f, 0.f, 0.f};
  for (int k = 0; k < K; ++k) {
    int e = ids[t * K + k] & 3;
    r[e] += wts[t * K + k];
  }
#pragma unroll
  for (int e = 0; e < 4; ++e) route4[e * T + t] = r[e];
}

__global__ __launch_bounds__(256) void cvt_bf16(const float* __restrict__ src,
                                                u16* __restrict__ dst, long n) {
  long i = ((long)blockIdx.x * 256 + threadIdx.x) * 4;
  if (i < n) {
    float4 f = *(const float4*)(src + i);
    u16x4 o;
    o.x = f2bf(f.x); o.y = f2bf(f.y); o.z = f2bf(f.z); o.w = f2bf(f.w);
    *(u16x4*)(dst + i) = o;
  }
}

// ---------- GEMM1: act[t,i] = silu(h1[t,i]) * h3[t,i] ----------
// A: hidden bf16 (T x H), W: w13[e] bf16 (2I x H) rows 0..I-1 = g1, I..2I-1 = g3
// Block tile: 128 (T) x 64 (i). Per K-step stages 64 g1-rows + 64 g3-rows of W.
__global__ __launch_bounds__(256, 2) void gemm1_act(const u16* __restrict__ A,
                                                    const u16* __restrict__ W,
                                                    u16* __restrict__ act,
                                                    int T, int H, int I) {
  __shared__ __align__(16) u16 sA[128 * 64];
  __shared__ __align__(16) u16 sB[128 * 64];
  const int tid = threadIdx.x;
  const int lane = tid & 63;
  const int wm = (tid >> 6) >> 1;  // wave row 0..1 (64 T-rows each)
  const int wn = (tid >> 6) & 1;   // wave col 0..1 (32 i-cols each)
  const int m0 = blockIdx.y * 128;
  const int n0 = blockIdx.x * 64;

  f32x4 acc1[4][2] = {};
  f32x4 acc3[4][2] = {};

  for (int k0 = 0; k0 < H; k0 += 64) {
    __syncthreads();
#pragma unroll
    for (int q = 0; q < 4; ++q) {
      int l = q * 256 + tid;
      int row = l >> 3;
      int cb = (l & 7) * 8;
      gld_lds16(A + (size_t)(m0 + row) * H + k0 + cb, &sA[l * 8]);
    }
#pragma unroll
    for (int q = 0; q < 4; ++q) {
      int l = q * 256 + tid;
      int row = l >> 3;
      int cb = (l & 7) * 8;
      int grow = (row < 64) ? (n0 + row) : (I + n0 + (row - 64));
      gld_lds16(W + (size_t)grow * H + k0 + cb, &sB[l * 8]);
    }
    __syncthreads();
#pragma unroll
    for (int kk = 0; kk < 64; kk += 32) {
      const int ko = kk + (lane >> 4) * 8;
      bf16x8 af[4];
#pragma unroll
      for (int mi = 0; mi < 4; ++mi)
        af[mi] = *(const bf16x8*)&sA[(wm * 64 + mi * 16 + (lane & 15)) * 64 + ko];
      bf16x8 b1[2], b3[2];
#pragma unroll
      for (int ni = 0; ni < 2; ++ni) {
        int r = wn * 32 + ni * 16 + (lane & 15);
        b1[ni] = *(const bf16x8*)&sB[r * 64 + ko];
        b3[ni] = *(const bf16x8*)&sB[(64 + r) * 64 + ko];
      }
#pragma unroll
      for (int mi = 0; mi < 4; ++mi)
#pragma unroll
        for (int ni = 0; ni < 2; ++ni) {
          acc1[mi][ni] = __builtin_amdgcn_mfma_f32_16x16x32_bf16(af[mi], b1[ni], acc1[mi][ni], 0, 0, 0);
          acc3[mi][ni] = __builtin_amdgcn_mfma_f32_16x16x32_bf16(af[mi], b3[ni], acc3[mi][ni], 0, 0, 0);
        }
    }
  }
  // epilogue: silu(g1)*g3, write bf16 act
  const int col = lane & 15;
  const int r0 = (lane >> 4) * 4;
#pragma unroll
  for (int mi = 0; mi < 4; ++mi)
#pragma unroll
    for (int ni = 0; ni < 2; ++ni)
#pragma unroll
      for (int r = 0; r < 4; ++r) {
        float c1 = acc1[mi][ni][r];
        float c3 = acc3[mi][ni][r];
        float v = c1 / (1.f + __expf(-c1)) * c3;
        int t = m0 + wm * 64 + mi * 16 + r0 + r;
        int i = n0 + wn * 32 + ni * 16 + col;
        act[(size_t)t * I + i] = f2bf(v);
      }
}

// ---------- GEMM2: out[t,h] (+)= route[t] * sum_i act[t,i]*w2[h,i] ----------
__global__ __launch_bounds__(256, 2) void gemm2_out(const u16* __restrict__ A,
                                                    const u16* __restrict__ W2,
                                                    const float* __restrict__ route,
                                                    float* __restrict__ out,
                                                    int T, int I, int H, int accum) {
  __shared__ __align__(16) u16 sA[128 * 64];
  __shared__ __align__(16) u16 sB[128 * 64];
  const int tid = threadIdx.x;
  const int lane = tid & 63;
  const int wm = (tid >> 6) >> 1;
  const int wn = (tid >> 6) & 1;
  const int m0 = blockIdx.y * 128;
  const int n0 = blockIdx.x * 128;

  f32x4 acc[4][4] = {};

  for (int k0 = 0; k0 < I; k0 += 64) {
    __syncthreads();
#pragma unroll
    for (int q = 0; q < 4; ++q) {
      int l = q * 256 + tid;
      int row = l >> 3;
      int cb = (l & 7) * 8;
      gld_lds16(A + (size_t)(m0 + row) * I + k0 + cb, &sA[l * 8]);
    }
#pragma unroll
    for (int q = 0; q < 4; ++q) {
      int l = q * 256 + tid;
      int row = l >> 3;
      int cb = (l & 7) * 8;
      gld_lds16(W2 + (size_t)(n0 + row) * I + k0 + cb, &sB[l * 8]);
    }
    __syncthreads();
#pragma unroll
    for (int kk = 0; kk < 64; kk += 32) {
      const int ko = kk + (lane >> 4) * 8;
      bf16x8 af[4], bf[4];
#pragma unroll
      for (int mi = 0; mi < 4; ++mi)
        af[mi] = *(const bf16x8*)&sA[(wm * 64 + mi * 16 + (lane & 15)) * 64 + ko];
#pragma unroll
      for (int ni = 0; ni < 4; ++ni)
        bf[ni] = *(const bf16x8*)&sB[(wn * 64 + ni * 16 + (lane & 15)) * 64 + ko];
#pragma unroll
      for (int mi = 0; mi < 4; ++mi)
#pragma unroll
        for (int ni = 0; ni < 4; ++ni)
          acc[mi][ni] = __builtin_amdgcn_mfma_f32_16x16x32_bf16(af[mi], bf[ni], acc[mi][ni], 0, 0, 0);
    }
  }
  const int col = lane & 15;
  const int r0 = (lane >> 4) * 4;
#pragma unroll
  for (int mi = 0; mi < 4; ++mi) {
#pragma unroll
    for (int r = 0; r < 4; ++r) {
      int t = m0 + wm * 64 + mi * 16 + r0 + r;
      float rt = route[t];
#pragma unroll
      for (int ni = 0; ni < 4; ++ni) {
        int h = n0 + wn * 64 + ni * 16 + col;
        size_t idx = (size_t)t * H + h;
        float v = rt * acc[mi][ni][r];
        if (accum) out[idx] += v; else out[idx] = v;
      }
    }
  }
}

// ---------- launch ----------

extern "C" void kernel_launch(void* const* d_in, const int* in_sizes, int n_in,
                              void* d_out, int out_size, void* d_ws, size_t ws_size,
                              hipStream_t stream) {
  constexpr int T = 2048, H = 2048, I = 5632, K = 2;
  const float* hidden = (const float*)d_in[0];
  const float* w13 = (const float*)d_in[1];
  const float* w2 = (const float*)d_in[2];
  const float* tw = (const float*)d_in[3];
  const int* tids = (const int*)d_in[4];
  float* out = (float*)d_out;

  // ws layout (bytes): route4 [0,32768) | hidden bf16 | w13[e] bf16 | w2[e] bf16 | act bf16
  const size_t OFF_HB = 32768;
  const size_t OFF_W13 = OFF_HB + (size_t)T * H * 2;          // 8421376
  const size_t OFF_W2 = OFF_W13 + (size_t)2 * I * H * 2;      // 54558720
  const size_t OFF_ACT = OFF_W2 + (size_t)H * I * 2;          // 77627392
  const size_t WS_NEED = OFF_ACT + (size_t)T * I * 2;         // 100696064
  if (ws_size < WS_NEED) return;  // insufficient scratch; bail rather than corrupt

  char* ws = (char*)d_ws;
  float* route4 = (float*)ws;
  u16* hb = (u16*)(ws + OFF_HB);
  u16* w13b = (u16*)(ws + OFF_W13);
  u16* w2b = (u16*)(ws + OFF_W2);
  u16* actb = (u16*)(ws + OFF_ACT);

  route_kernel<<<(T + 255) / 256, 256, 0, stream>>>(tids, tw, route4, T, K);

  const long nh = (long)T * H;
  cvt_bf16<<<(int)((nh / 4 + 255) / 256), 256, 0, stream>>>(hidden, hb, nh);

  const long nw13 = (long)2 * I * H;
  const long nw2 = (long)H * I;
  dim3 g1(I / 64, T / 128);
  dim3 g2(H / 128, T / 128);

  for (int e = 0; e < 4; ++e) {
    cvt_bf16<<<(int)((nw13 / 4 + 255) / 256), 256, 0, stream>>>(w13 + (size_t)e * nw13, w13b, nw13);
    gemm1_act<<<g1, 256, 0, stream>>>(hb, w13b, actb, T, H, I);
    cvt_bf16<<<(int)((nw2 / 4 + 255) / 256), 256, 0, stream>>>(w2 + (size_t)e * nw2, w2b, nw2);
    gemm2_out<<<g2, 256, 0, stream>>>(actb, w2b, route4 + e * T, out, T, I, H, e != 0);
  }
}

// Round 2
// 1807.575 us; speedup vs baseline: 1.1422x; 1.1422x over previous
//
#include <hip/hip_runtime.h>

typedef float f32x4 __attribute__((ext_vector_type(4)));
typedef __bf16 bf16x8 __attribute__((ext_vector_type(8)));
typedef unsigned short u16;
typedef u16 u16x4 __attribute__((ext_vector_type(4)));

// ---------- helpers ----------

__device__ __forceinline__ u16 f2bf(float x) {
  union { float f; unsigned int u; } v; v.f = x;
  unsigned int u = v.u;
  return (u16)((u + 0x7FFFu + ((u >> 16) & 1u)) >> 16);  // RNE
}

__device__ __forceinline__ void gld_lds16(const void* g, void* l) {
  // async global->LDS, 16B per lane; LDS dest is wave-uniform base + lane*16
  __builtin_amdgcn_global_load_lds((const __attribute__((address_space(1))) void*)g,
                                   (__attribute__((address_space(3))) void*)l,
                                   16, 0, 0);
}

// ---------- small kernels ----------

// route4[e*T + t] = sum_k topk_weights[t,k] * (topk_ids[t,k] % 4 == e)
__global__ __launch_bounds__(256) void route_kernel(const int* __restrict__ ids,
                                                    const float* __restrict__ wts,
                                                    float* __restrict__ route4,
                                                    int T, int K) {
  int t = blockIdx.x * 256 + threadIdx.x;
  if (t >= T) return;
  float r[4] = {0.f, 0.f, 0.f, 0.f};
  for (int k = 0; k < K; ++k) {
    int e = ids[t * K + k] & 3;
    r[e] += wts[t * K + k];
  }
#pragma unroll
  for (int e = 0; e < 4; ++e) route4[e * T + t] = r[e];
}

__global__ __launch_bounds__(256) void cvt_bf16(const float* __restrict__ src,
                                                u16* __restrict__ dst, long n) {
  long i = ((long)blockIdx.x * 256 + threadIdx.x) * 4;
  if (i < n) {
    float4 f = *(const float4*)(src + i);
    u16x4 o;
    o.x = f2bf(f.x); o.y = f2bf(f.y); o.z = f2bf(f.z); o.w = f2bf(f.w);
    *(u16x4*)(dst + i) = o;
  }
}

// ---------- GEMM1 (all 4 experts via blockIdx.z) ----------
// act_e[t,i] = route[e,t] * silu(g1) * g3
// A: hidden bf16 (T x H); Wall: 4 experts of (2I x H) bf16, rows 0..I-1=g1, I..2I-1=g3
__global__ __launch_bounds__(256, 2) void gemm1_act(const u16* __restrict__ A,
                                                    const u16* __restrict__ Wall,
                                                    const float* __restrict__ route4,
                                                    u16* __restrict__ actall,
                                                    int T, int H, int I) {
  __shared__ __align__(16) u16 sA[128 * 64];
  __shared__ __align__(16) u16 sB[128 * 64];
  const int e = blockIdx.z;
  const u16* W = Wall + (size_t)e * 2 * I * H;
  u16* act = actall + (size_t)e * T * I;
  const int tid = threadIdx.x;
  const int lane = tid & 63;
  const int wm = (tid >> 6) >> 1;  // wave row 0..1 (64 T-rows each)
  const int wn = (tid >> 6) & 1;   // wave col 0..1 (32 i-cols each)
  const int m0 = blockIdx.y * 128;
  const int n0 = blockIdx.x * 64;

  f32x4 acc1[4][2] = {};
  f32x4 acc3[4][2] = {};

  for (int k0 = 0; k0 < H; k0 += 64) {
    __syncthreads();
#pragma unroll
    for (int q = 0; q < 4; ++q) {
      int l = q * 256 + tid;
      int row = l >> 3;
      int cb = (l & 7) * 8;
      gld_lds16(A + (size_t)(m0 + row) * H + k0 + cb, &sA[l * 8]);
    }
#pragma unroll
    for (int q = 0; q < 4; ++q) {
      int l = q * 256 + tid;
      int row = l >> 3;
      int cb = (l & 7) * 8;
      int grow = (row < 64) ? (n0 + row) : (I + n0 + (row - 64));
      gld_lds16(W + (size_t)grow * H + k0 + cb, &sB[l * 8]);
    }
    __syncthreads();
#pragma unroll
    for (int kk = 0; kk < 64; kk += 32) {
      const int ko = kk + (lane >> 4) * 8;
      bf16x8 af[4];
#pragma unroll
      for (int mi = 0; mi < 4; ++mi)
        af[mi] = *(const bf16x8*)&sA[(wm * 64 + mi * 16 + (lane & 15)) * 64 + ko];
      bf16x8 b1[2], b3[2];
#pragma unroll
      for (int ni = 0; ni < 2; ++ni) {
        int r = wn * 32 + ni * 16 + (lane & 15);
        b1[ni] = *(const bf16x8*)&sB[r * 64 + ko];
        b3[ni] = *(const bf16x8*)&sB[(64 + r) * 64 + ko];
      }
#pragma unroll
      for (int mi = 0; mi < 4; ++mi)
#pragma unroll
        for (int ni = 0; ni < 2; ++ni) {
          acc1[mi][ni] = __builtin_amdgcn_mfma_f32_16x16x32_bf16(af[mi], b1[ni], acc1[mi][ni], 0, 0, 0);
          acc3[mi][ni] = __builtin_amdgcn_mfma_f32_16x16x32_bf16(af[mi], b3[ni], acc3[mi][ni], 0, 0, 0);
        }
    }
  }
  // epilogue: route * silu(g1) * g3 -> bf16 act
  const int col = lane & 15;
  const int r0 = (lane >> 4) * 4;
#pragma unroll
  for (int mi = 0; mi < 4; ++mi)
#pragma unroll
    for (int r = 0; r < 4; ++r) {
      int t = m0 + wm * 64 + mi * 16 + r0 + r;
      float rt = route4[e * T + t];
#pragma unroll
      for (int ni = 0; ni < 2; ++ni) {
        float c1 = acc1[mi][ni][r];
        float c3 = acc3[mi][ni][r];
        float v = rt * (c1 / (1.f + __expf(-c1)) * c3);
        int i = n0 + wn * 32 + ni * 16 + col;
        act[(size_t)t * I + i] = f2bf(v);
      }
    }
}

// ---------- GEMM2 (all 4 experts via blockIdx.z, atomic accumulate) ----------
// out[t,h] += sum_i act_e[t,i] * w2_e[h,i]   (route already folded into act)
__global__ __launch_bounds__(256, 2) void gemm2_out(const u16* __restrict__ Aall,
                                                    const u16* __restrict__ W2all,
                                                    float* __restrict__ out,
                                                    int T, int I, int H) {
  __shared__ __align__(16) u16 sA[128 * 64];
  __shared__ __align__(16) u16 sB[128 * 64];
  const int e = blockIdx.z;
  const u16* A = Aall + (size_t)e * T * I;
  const u16* W2 = W2all + (size_t)e * H * I;
  const int tid = threadIdx.x;
  const int lane = tid & 63;
  const int wm = (tid >> 6) >> 1;
  const int wn = (tid >> 6) & 1;
  const int m0 = blockIdx.y * 128;
  const int n0 = blockIdx.x * 128;

  f32x4 acc[4][4] = {};

  for (int k0 = 0; k0 < I; k0 += 64) {
    __syncthreads();
#pragma unroll
    for (int q = 0; q < 4; ++q) {
      int l = q * 256 + tid;
      int row = l >> 3;
      int cb = (l & 7) * 8;
      gld_lds16(A + (size_t)(m0 + row) * I + k0 + cb, &sA[l * 8]);
    }
#pragma unroll
    for (int q = 0; q < 4; ++q) {
      int l = q * 256 + tid;
      int row = l >> 3;
      int cb = (l & 7) * 8;
      gld_lds16(W2 + (size_t)(n0 + row) * I + k0 + cb, &sB[l * 8]);
    }
    __syncthreads();
#pragma unroll
    for (int kk = 0; kk < 64; kk += 32) {
      const int ko = kk + (lane >> 4) * 8;
      bf16x8 af[4], bfr[4];
#pragma unroll
      for (int mi = 0; mi < 4; ++mi)
        af[mi] = *(const bf16x8*)&sA[(wm * 64 + mi * 16 + (lane & 15)) * 64 + ko];
#pragma unroll
      for (int ni = 0; ni < 4; ++ni)
        bfr[ni] = *(const bf16x8*)&sB[(wn * 64 + ni * 16 + (lane & 15)) * 64 + ko];
#pragma unroll
      for (int mi = 0; mi < 4; ++mi)
#pragma unroll
        for (int ni = 0; ni < 4; ++ni)
          acc[mi][ni] = __builtin_amdgcn_mfma_f32_16x16x32_bf16(af[mi], bfr[ni], acc[mi][ni], 0, 0, 0);
    }
  }
  const int col = lane & 15;
  const int r0 = (lane >> 4) * 4;
#pragma unroll
  for (int mi = 0; mi < 4; ++mi)
#pragma unroll
    for (int r = 0; r < 4; ++r) {
      int t = m0 + wm * 64 + mi * 16 + r0 + r;
#pragma unroll
      for (int ni = 0; ni < 4; ++ni) {
        int h = n0 + wn * 64 + ni * 16 + col;
        unsafeAtomicAdd(&out[(size_t)t * H + h], acc[mi][ni][r]);
      }
    }
}

// ---------- launch ----------

extern "C" void kernel_launch(void* const* d_in, const int* in_sizes, int n_in,
                              void* d_out, int out_size, void* d_ws, size_t ws_size,
                              hipStream_t stream) {
  constexpr int T = 2048, H = 2048, I = 5632, K = 2;
  const float* hidden = (const float*)d_in[0];
  const float* w13 = (const float*)d_in[1];
  const float* w2 = (const float*)d_in[2];
  const float* tw = (const float*)d_in[3];
  const int* tids = (const int*)d_in[4];
  float* out = (float*)d_out;

  // ws layout (bytes): route4 | hb | w13b[0..3] | w2b[0..3] | actb[0..3]
  const size_t OFF_HB = 32768;
  const size_t OFF_W13 = OFF_HB + (size_t)T * H * 2;                 // +8 MB
  const size_t OFF_W2 = OFF_W13 + (size_t)4 * 2 * I * H * 2;         // +184.5 MB
  const size_t OFF_ACT = OFF_W2 + (size_t)4 * H * I * 2;             // +92.3 MB
  const size_t WS_NEED = OFF_ACT + (size_t)4 * T * I * 2;            // ~377.5 MB
  if (ws_size < WS_NEED) return;

  char* ws = (char*)d_ws;
  float* route4 = (float*)ws;
  u16* hb = (u16*)(ws + OFF_HB);
  u16* w13b = (u16*)(ws + OFF_W13);
  u16* w2b = (u16*)(ws + OFF_W2);
  u16* actb = (u16*)(ws + OFF_ACT);

  route_kernel<<<(T + 255) / 256, 256, 0, stream>>>(tids, tw, route4, T, K);

  const long nh = (long)T * H;
  cvt_bf16<<<(int)((nh / 4 + 255) / 256), 256, 0, stream>>>(hidden, hb, nh);
  const long nw13 = (long)4 * 2 * I * H;  // experts 0..3 contiguous
  cvt_bf16<<<(int)((nw13 / 4 + 255) / 256), 256, 0, stream>>>(w13, w13b, nw13);
  const long nw2 = (long)4 * H * I;
  cvt_bf16<<<(int)((nw2 / 4 + 255) / 256), 256, 0, stream>>>(w2, w2b, nw2);

  hipMemsetAsync(out, 0, (size_t)out_size * 4, stream);

  dim3 g1(I / 64, T / 128, 4);
  gemm1_act<<<g1, 256, 0, stream>>>(hb, w13b, route4, actb, T, H, I);

  dim3 g2(H / 128, T / 128, 4);
  gemm2_out<<<g2, 256, 0, stream>>>(actb, w2b, out, T, I, H);
}

// Round 3
// 1608.577 us; speedup vs baseline: 1.2835x; 1.1237x over previous
//
#include <hip/hip_runtime.h>

typedef float f32x4 __attribute__((ext_vector_type(4)));
typedef __bf16 bf16x8 __attribute__((ext_vector_type(8)));
typedef unsigned short u16;
typedef u16 u16x4 __attribute__((ext_vector_type(4)));

// ---------- helpers ----------

__device__ __forceinline__ u16 f2bf(float x) {
  union { float f; unsigned int u; } v; v.f = x;
  unsigned int u = v.u;
  return (u16)((u + 0x7FFFu + ((u >> 16) & 1u)) >> 16);  // RNE
}

__device__ __forceinline__ void gld_lds16(const void* g, void* l) {
  // async global->LDS, 16B per lane; LDS dest is wave-uniform base + lane*16
  __builtin_amdgcn_global_load_lds((const __attribute__((address_space(1))) void*)g,
                                   (__attribute__((address_space(3))) void*)l,
                                   16, 0, 0);
}

// LDS tile layout (128 rows x 64 u16): 16B granule (r, g) stored at physical
// granule g ^ (r & 7). Kills the 16-way bank conflict of the unswizzled
// row-stride-128B layout; fragment reads become 2-way aliased (free, m136).

// ---------- small kernels ----------

__global__ __launch_bounds__(256) void route_kernel(const int* __restrict__ ids,
                                                    const float* __restrict__ wts,
                                                    float* __restrict__ route4,
                                                    int T, int K) {
  int t = blockIdx.x * 256 + threadIdx.x;
  if (t >= T) return;
  float r[4] = {0.f, 0.f, 0.f, 0.f};
  for (int k = 0; k < K; ++k) {
    int e = ids[t * K + k] & 3;
    r[e] += wts[t * K + k];
  }
#pragma unroll
  for (int e = 0; e < 4; ++e) route4[e * T + t] = r[e];
}

__global__ __launch_bounds__(256) void cvt_bf16(const float* __restrict__ src,
                                                u16* __restrict__ dst, long n) {
  long i = ((long)blockIdx.x * 256 + threadIdx.x) * 4;
  if (i < n) {
    float4 f = *(const float4*)(src + i);
    u16x4 o;
    o.x = f2bf(f.x); o.y = f2bf(f.y); o.z = f2bf(f.z); o.w = f2bf(f.w);
    *(u16x4*)(dst + i) = o;
  }
}

// out[i] = sum_e part[e*n + i]
__global__ __launch_bounds__(256) void combine4(const float* __restrict__ part,
                                                float* __restrict__ out, long n) {
  long i = ((long)blockIdx.x * 256 + threadIdx.x) * 4;
  if (i < n) {
    f32x4 a = *(const f32x4*)(part + i);
    f32x4 b = *(const f32x4*)(part + n + i);
    f32x4 c = *(const f32x4*)(part + 2 * n + i);
    f32x4 d = *(const f32x4*)(part + 3 * n + i);
    *(f32x4*)(out + i) = (a + b) + (c + d);
  }
}

// ---------- GEMM1 (all 4 experts via blockIdx.z) ----------
// act_e[t,i] = route[e,t] * silu(g1) * g3
__global__ __launch_bounds__(256, 4) void gemm1_act(const u16* __restrict__ A,
                                                    const u16* __restrict__ Wall,
                                                    const float* __restrict__ route4,
                                                    u16* __restrict__ actall,
                                                    int T, int H, int I) {
  __shared__ __align__(16) u16 sA[128 * 64];
  __shared__ __align__(16) u16 sB[128 * 64];
  const int e = blockIdx.z;
  const u16* W = Wall + (size_t)e * 2 * I * H;
  u16* act = actall + (size_t)e * T * I;
  const int tid = threadIdx.x;
  const int lane = tid & 63;
  const int wm = (tid >> 6) >> 1;
  const int wn = (tid >> 6) & 1;
  const int m0 = blockIdx.y * 128;
  const int n0 = blockIdx.x * 64;

  f32x4 acc1[4][2] = {};
  f32x4 acc3[4][2] = {};

  for (int k0 = 0; k0 < H; k0 += 64) {
    __syncthreads();
#pragma unroll
    for (int q = 0; q < 4; ++q) {
      int l = q * 256 + tid;
      int row = l >> 3;
      int gg = (l ^ (l >> 3)) & 7;  // swizzled source granule
      gld_lds16(A + (size_t)(m0 + row) * H + k0 + gg * 8, &sA[l * 8]);
    }
#pragma unroll
    for (int q = 0; q < 4; ++q) {
      int l = q * 256 + tid;
      int row = l >> 3;
      int gg = (l ^ (l >> 3)) & 7;
      int grow = (row < 64) ? (n0 + row) : (I + n0 + (row - 64));
      gld_lds16(W + (size_t)grow * H + k0 + gg * 8, &sB[l * 8]);
    }
    __syncthreads();
#pragma unroll
    for (int kk = 0; kk < 64; kk += 32) {
      const int gbase = (kk >> 3) + (lane >> 4);
      const int swzo = ((gbase ^ (lane & 7)) << 3);  // rows here are ≡ lane (mod 8)
      bf16x8 af[4];
#pragma unroll
      for (int mi = 0; mi < 4; ++mi)
        af[mi] = *(const bf16x8*)&sA[(wm * 64 + mi * 16 + (lane & 15)) * 64 + swzo];
      bf16x8 b1[2], b3[2];
#pragma unroll
      for (int ni = 0; ni < 2; ++ni) {
        int r = wn * 32 + ni * 16 + (lane & 15);
        b1[ni] = *(const bf16x8*)&sB[r * 64 + swzo];
        b3[ni] = *(const bf16x8*)&sB[(64 + r) * 64 + swzo];
      }
#pragma unroll
      for (int mi = 0; mi < 4; ++mi)
#pragma unroll
        for (int ni = 0; ni < 2; ++ni) {
          acc1[mi][ni] = __builtin_amdgcn_mfma_f32_16x16x32_bf16(af[mi], b1[ni], acc1[mi][ni], 0, 0, 0);
          acc3[mi][ni] = __builtin_amdgcn_mfma_f32_16x16x32_bf16(af[mi], b3[ni], acc3[mi][ni], 0, 0, 0);
        }
    }
  }
  const int col = lane & 15;
  const int r0 = (lane >> 4) * 4;
#pragma unroll
  for (int mi = 0; mi < 4; ++mi)
#pragma unroll
    for (int r = 0; r < 4; ++r) {
      int t = m0 + wm * 64 + mi * 16 + r0 + r;
      float rt = route4[e * T + t];
#pragma unroll
      for (int ni = 0; ni < 2; ++ni) {
        float c1 = acc1[mi][ni][r];
        float c3 = acc3[mi][ni][r];
        float v = rt * (c1 / (1.f + __expf(-c1)) * c3);
        int i = n0 + wn * 32 + ni * 16 + col;
        act[(size_t)t * I + i] = f2bf(v);
      }
    }
}

// ---------- GEMM2: per-expert partials, no atomics ----------
// part[e][t,h] = sum_i act_e[t,i] * w2_e[h,i]
__global__ __launch_bounds__(256, 4) void gemm2_part(const u16* __restrict__ Aall,
                                                     const u16* __restrict__ W2all,
                                                     float* __restrict__ part,
                                                     int T, int I, int H) {
  __shared__ __align__(16) u16 sA[128 * 64];
  __shared__ __align__(16) u16 sB[128 * 64];
  const int e = blockIdx.z;
  const u16* A = Aall + (size_t)e * T * I;
  const u16* W2 = W2all + (size_t)e * H * I;
  float* myout = part + (size_t)e * T * H;
  const int tid = threadIdx.x;
  const int lane = tid & 63;
  const int wm = (tid >> 6) >> 1;
  const int wn = (tid >> 6) & 1;
  const int m0 = blockIdx.y * 128;
  const int n0 = blockIdx.x * 128;

  f32x4 acc[4][4] = {};

  for (int k0 = 0; k0 < I; k0 += 64) {
    __syncthreads();
#pragma unroll
    for (int q = 0; q < 4; ++q) {
      int l = q * 256 + tid;
      int row = l >> 3;
      int gg = (l ^ (l >> 3)) & 7;
      gld_lds16(A + (size_t)(m0 + row) * I + k0 + gg * 8, &sA[l * 8]);
    }
#pragma unroll
    for (int q = 0; q < 4; ++q) {
      int l = q * 256 + tid;
      int row = l >> 3;
      int gg = (l ^ (l >> 3)) & 7;
      gld_lds16(W2 + (size_t)(n0 + row) * I + k0 + gg * 8, &sB[l * 8]);
    }
    __syncthreads();
#pragma unroll
    for (int kk = 0; kk < 64; kk += 32) {
      const int gbase = (kk >> 3) + (lane >> 4);
      const int swzo = ((gbase ^ (lane & 7)) << 3);
      bf16x8 af[4], bfr[4];
#pragma unroll
      for (int mi = 0; mi < 4; ++mi)
        af[mi] = *(const bf16x8*)&sA[(wm * 64 + mi * 16 + (lane & 15)) * 64 + swzo];
#pragma unroll
      for (int ni = 0; ni < 4; ++ni)
        bfr[ni] = *(const bf16x8*)&sB[(wn * 64 + ni * 16 + (lane & 15)) * 64 + swzo];
#pragma unroll
      for (int mi = 0; mi < 4; ++mi)
#pragma unroll
        for (int ni = 0; ni < 4; ++ni)
          acc[mi][ni] = __builtin_amdgcn_mfma_f32_16x16x32_bf16(af[mi], bfr[ni], acc[mi][ni], 0, 0, 0);
    }
  }
  const int col = lane & 15;
  const int r0 = (lane >> 4) * 4;
#pragma unroll
  for (int mi = 0; mi < 4; ++mi)
#pragma unroll
    for (int r = 0; r < 4; ++r) {
      int t = m0 + wm * 64 + mi * 16 + r0 + r;
#pragma unroll
      for (int ni = 0; ni < 4; ++ni) {
        int h = n0 + wn * 64 + ni * 16 + col;
        myout[(size_t)t * H + h] = acc[mi][ni][r];
      }
    }
}

// ---------- launch ----------

extern "C" void kernel_launch(void* const* d_in, const int* in_sizes, int n_in,
                              void* d_out, int out_size, void* d_ws, size_t ws_size,
                              hipStream_t stream) {
  constexpr int T = 2048, H = 2048, I = 5632, K = 2;
  const float* hidden = (const float*)d_in[0];
  const float* w13 = (const float*)d_in[1];
  const float* w2 = (const float*)d_in[2];
  const float* tw = (const float*)d_in[3];
  const int* tids = (const int*)d_in[4];
  float* out = (float*)d_out;

  // ws layout: route4 | hb | w13b[0..3] | w2b[0..3] | actb[0..3] | part[0..3]
  const size_t OFF_HB = 32768;
  const size_t OFF_W13 = OFF_HB + (size_t)T * H * 2;
  const size_t OFF_W2 = OFF_W13 + (size_t)4 * 2 * I * H * 2;
  const size_t OFF_ACT = OFF_W2 + (size_t)4 * H * I * 2;
  const size_t OFF_PART = OFF_ACT + (size_t)4 * T * I * 2;
  const size_t WS_NEED = OFF_PART + (size_t)4 * T * H * 4;  // ~444.7 MB
  if (ws_size < WS_NEED) return;

  char* ws = (char*)d_ws;
  float* route4 = (float*)ws;
  u16* hb = (u16*)(ws + OFF_HB);
  u16* w13b = (u16*)(ws + OFF_W13);
  u16* w2b = (u16*)(ws + OFF_W2);
  u16* actb = (u16*)(ws + OFF_ACT);
  float* partb = (float*)(ws + OFF_PART);

  route_kernel<<<(T + 255) / 256, 256, 0, stream>>>(tids, tw, route4, T, K);

  const long nh = (long)T * H;
  cvt_bf16<<<(int)((nh / 4 + 255) / 256), 256, 0, stream>>>(hidden, hb, nh);
  const long nw13 = (long)4 * 2 * I * H;
  cvt_bf16<<<(int)((nw13 / 4 + 255) / 256), 256, 0, stream>>>(w13, w13b, nw13);
  const long nw2 = (long)4 * H * I;
  cvt_bf16<<<(int)((nw2 / 4 + 255) / 256), 256, 0, stream>>>(w2, w2b, nw2);

  dim3 g1(I / 64, T / 128, 4);
  gemm1_act<<<g1, 256, 0, stream>>>(hb, w13b, route4, actb, T, H, I);

  dim3 g2(H / 128, T / 128, 4);
  gemm2_part<<<g2, 256, 0, stream>>>(actb, w2b, partb, T, I, H);

  const long nout = (long)T * H;
  combine4<<<(int)((nout / 4 + 255) / 256), 256, 0, stream>>>(partb, out, nout);
}